// Round 8
// baseline (307.431 us; speedup 1.0000x reference)
//
#include <hip/hip_runtime.h>

// CapsuleLayer dynamic routing, MI355X (gfx950).
// B=64, I=2048 (input caps), L=16 (in_dim), J=64 (out caps), K=32 (out dim).
// u_hat never materialized. Logits are linear in u_hat (b_r = (sum of prior v).u_hat).
// Per routing iteration r>0:
//   zsm2: block owns 4 i x ALL 64 j -> e via MFMA into LDS, denominator in-LDS,
//         store premultiplied c[j][i][b] = e/sum_j e (f16, coalesced). No dsum pass.
//   s:    s[b,j,k] partials = sum_i c*u_hat via MFMA (wave owns j, streams i),
//         coalesced parts[ch][j][k][b] flush (R6 lesson: scatter = 11x write amp).
//   reduce: block=j, lane=b; squash; maintain wv fragments (f16, MFMA D-layout).
// r=0: s0_cast fuses the W fp32->f16 cast (single HBM read of W = the floor).
// MFMA 32x32x16 f16: D rows k = (r&3)+8*(r>>2)+4*(lane>>5), cols b = lane&31.

#define B_ 64
#define I_ 2048
#define L_ 16
#define J_ 64
#define K_ 32
#define N_ 2048  // J_*K_

typedef _Float16 half8_t __attribute__((ext_vector_type(8)));
typedef float f32x16 __attribute__((ext_vector_type(16)));
typedef float float4_t __attribute__((ext_vector_type(4)));

__device__ __forceinline__ f32x16 fzero16() {
    f32x16 z;
#pragma unroll
    for (int r = 0; r < 16; ++r) z[r] = 0.f;
    return z;
}

// ---- cast x: [b][i][l] fp32 -> Xh[i][b][l] f16
__global__ __launch_bounds__(256) void cast_x_kernel(const float* __restrict__ X,
                                                     _Float16* __restrict__ Xh) {
    unsigned tid = blockIdx.x * 256u + threadIdx.x;  // (i,b), b fastest
    unsigned b = tid & 63u;
    unsigned i = tid >> 6;
    const float4_t* src = (const float4_t*)(X + (size_t)(b * I_ + i) * L_);
    float4_t f0 = src[0], f1 = src[1], f2 = src[2], f3 = src[3];
    half8_t h0, h1;
#pragma unroll
    for (int e = 0; e < 4; ++e) {
        h0[e] = (_Float16)f0[e];
        h0[4 + e] = (_Float16)f1[e];
        h1[e] = (_Float16)f2[e];
        h1[4 + e] = (_Float16)f3[e];
    }
    _Float16* dst = Xh + (size_t)(i * B_ + b) * L_;
    *(half8_t*)dst = h0;
    *(half8_t*)(dst + 8) = h1;
}

// ---- r0 pass: uniform c (1/64 folded into reduce); fused W fp32 read + f16 cast.
// Grid: SCH*8 blocks x 512 threads; wave owns j = (blk&7)*8 + w, streams i-chunk.
__global__ __launch_bounds__(512) void s0_cast_kernel(const float* __restrict__ Wf,
                                                      _Float16* __restrict__ Wh_out,
                                                      const _Float16* __restrict__ Xh,
                                                      _Float16* __restrict__ parts,
                                                      int SCH, int ICH) {
    const int tid = threadIdx.x;
    const int w = tid >> 6;
    const int l = tid & 63;
    const int h2 = l >> 5;
    const int kb = l & 31;
    const int chunk = blockIdx.x >> 3;
    const int jq = blockIdx.x & 7;
    const int j = jq * 8 + w;

    float s0[16], s1[16];
#pragma unroll
    for (int r = 0; r < 16; ++r) { s0[r] = 0.f; s1[r] = 0.f; }

    const int i0 = chunk * ICH;
    for (int ii = 0; ii < ICH; ++ii) {
        const int i = i0 + ii;
        const _Float16* xb = Xh + (size_t)i * (B_ * L_);
        half8_t xf0 = *(const half8_t*)(xb + kb * L_ + 8 * h2);
        half8_t xf1 = *(const half8_t*)(xb + (32 + kb) * L_ + 8 * h2);
        const float4_t* wsrc =
            (const float4_t*)(Wf + ((size_t)(j * I_ + i) * K_ + kb) * L_ + 8 * h2);
        float4_t a0 = wsrc[0], a1 = wsrc[1];
        half8_t af;
#pragma unroll
        for (int e = 0; e < 4; ++e) {
            af[e] = (_Float16)a0[e];
            af[4 + e] = (_Float16)a1[e];
        }
        *(half8_t*)(Wh_out + ((size_t)(i * J_ + j) * K_ + kb) * L_ + 8 * h2) = af;
        f32x16 acc0 = __builtin_amdgcn_mfma_f32_32x32x16_f16(af, xf0, fzero16(), 0, 0, 0);
        f32x16 acc1 = __builtin_amdgcn_mfma_f32_32x32x16_f16(af, xf1, fzero16(), 0, 0, 0);
#pragma unroll
        for (int r = 0; r < 16; ++r) {
            s0[r] += acc0[r];
            s1[r] += acc1[r];
        }
    }
    // coalesced flush: parts[chunk][j][k][b]; per r, lanes write full 64B lines
#pragma unroll
    for (int r = 0; r < 16; ++r) {
        const int k = (r & 3) + 8 * (r >> 2) + 4 * h2;
        _Float16* p = parts + (((size_t)chunk * J_ + j) * K_ + k) * B_;
        p[kb] = (_Float16)s0[r];
        p[32 + kb] = (_Float16)s1[r];
    }
}

// ---- zsm2: logits + softmax -> premultiplied c[j][i][b] (f16), one kernel.
// Grid: I_/4 = 512 blocks x 512 threads (8 waves). Block owns 4 i x all 64 j.
// Phase 1: wave w computes e for j in [8w, 8w+8) x 4 i -> LDS.
// Phase 2: waves 0-3 compute rdl[i][b] = 1/sum_j e in-LDS.
// Phase 3: all waves store c = e * rdl, coalesced (128 B per (j,i) row).
// wvz layout: [j][h2][b:64][r:16] f16 where k = (r&3) + 8*(r>>2) + 4*h2.
__global__ __launch_bounds__(512) void zsm2_kernel(const _Float16* __restrict__ Wh,
                                                   const _Float16* __restrict__ Xh,
                                                   const _Float16* __restrict__ wvz,
                                                   _Float16* __restrict__ cbuf) {
    __shared__ _Float16 elds[J_ * 4 * B_];  // [j][i_local][b] = 32 KB
    __shared__ float rdl[4 * B_];           // 1 KB
    const int tid = threadIdx.x;
    const int w = tid >> 6;
    const int l = tid & 63;
    const int h2 = l >> 5;
    const int kb = l & 31;
    const int i0 = blockIdx.x * 4;

    // x fragments for the 4 local i
    half8_t xf0[4], xf1[4];
#pragma unroll
    for (int ii = 0; ii < 4; ++ii) {
        const _Float16* xb = Xh + (size_t)(i0 + ii) * (B_ * L_);
        xf0[ii] = *(const half8_t*)(xb + kb * L_ + 8 * h2);
        xf1[ii] = *(const half8_t*)(xb + (32 + kb) * L_ + 8 * h2);
    }

    // ---- phase 1: e = exp(wv . u_hat)
#pragma unroll
    for (int jj = 0; jj < 8; ++jj) {
        const int j = w * 8 + jj;
        const _Float16* wp = wvz + ((size_t)(j * 2 + h2) * B_ + kb) * 16;
        const half8_t wv00 = *(const half8_t*)wp;          // batch kb,    regs 0-7
        const half8_t wv01 = *(const half8_t*)(wp + 8);    // batch kb,    regs 8-15
        const half8_t wv10 = *(const half8_t*)(wp + 512);  // batch kb+32, regs 0-7
        const half8_t wv11 = *(const half8_t*)(wp + 520);
#pragma unroll
        for (int ii = 0; ii < 4; ++ii) {
            half8_t af = *(const half8_t*)(Wh +
                ((size_t)((i0 + ii) * J_ + j) * K_ + kb) * L_ + 8 * h2);
            f32x16 acc0 = __builtin_amdgcn_mfma_f32_32x32x16_f16(af, xf0[ii], fzero16(), 0, 0, 0);
            f32x16 acc1 = __builtin_amdgcn_mfma_f32_32x32x16_f16(af, xf1[ii], fzero16(), 0, 0, 0);
            // 4 independent partial chains per z (dep depth 4)
            float z0a = 0.f, z0b = 0.f, z0c = 0.f, z0d = 0.f;
            float z1a = 0.f, z1b = 0.f, z1c = 0.f, z1d = 0.f;
#pragma unroll
            for (int r = 0; r < 4; ++r) {
                z0a += acc0[r]      * (float)wv00[r];
                z0b += acc0[r + 4]  * (float)wv00[r + 4];
                z0c += acc0[r + 8]  * (float)wv01[r];
                z0d += acc0[r + 12] * (float)wv01[r + 4];
                z1a += acc1[r]      * (float)wv10[r];
                z1b += acc1[r + 4]  * (float)wv10[r + 4];
                z1c += acc1[r + 8]  * (float)wv11[r];
                z1d += acc1[r + 12] * (float)wv11[r + 4];
            }
            float z0 = (z0a + z0b) + (z0c + z0d);
            float z1 = (z1a + z1b) + (z1c + z1d);
            z0 += __shfl_xor(z0, 32, 64);  // combine disjoint k-halves
            z1 += __shfl_xor(z1, 32, 64);
            // lane l holds full logit of batch l; |z| <~ 6, clamp = NaN insurance
            const float zf = fminf((l < 32) ? z0 : z1, 11.0f);
            elds[((size_t)j * 4 + ii) * B_ + l] = (_Float16)__expf(zf);
        }
    }
    __syncthreads();

    // ---- phase 2: rdl[i][b] = 1/sum_j e ; waves 0-3 handle i_local = w, lane = b
    if (w < 4) {
        float p0 = 0.f, p1 = 0.f, p2 = 0.f, p3 = 0.f;
#pragma unroll
        for (int jq = 0; jq < 16; ++jq) {
            p0 += (float)elds[((size_t)(jq * 4 + 0) * 4 + w) * B_ + l];
            p1 += (float)elds[((size_t)(jq * 4 + 1) * 4 + w) * B_ + l];
            p2 += (float)elds[((size_t)(jq * 4 + 2) * 4 + w) * B_ + l];
            p3 += (float)elds[((size_t)(jq * 4 + 3) * 4 + w) * B_ + l];
        }
        rdl[w * B_ + l] = 1.0f / ((p0 + p1) + (p2 + p3));
    }
    __syncthreads();

    // ---- phase 3: store c[j][i][b] = e * rdl, coalesced
#pragma unroll
    for (int jj = 0; jj < 8; ++jj) {
        const int j = w * 8 + jj;
#pragma unroll
        for (int ii = 0; ii < 4; ++ii) {
            const float c = (float)elds[((size_t)j * 4 + ii) * B_ + l] * rdl[ii * B_ + l];
            cbuf[((size_t)j * I_ + (i0 + ii)) * B_ + l] = (_Float16)c;
        }
    }
}

// ---- S: s partials over an i-chunk, weighted by premultiplied c. 4-deep MLP.
__global__ __launch_bounds__(512) void s_kernel(const _Float16* __restrict__ Wh,
                                                const _Float16* __restrict__ Xh,
                                                const _Float16* __restrict__ cbuf,
                                                _Float16* __restrict__ parts,
                                                int SCH, int ICH) {
    const int tid = threadIdx.x;
    const int w = tid >> 6;
    const int l = tid & 63;
    const int h2 = l >> 5;
    const int kb = l & 31;
    const int chunk = blockIdx.x >> 3;
    const int jq = blockIdx.x & 7;
    const int j = jq * 8 + w;

    float s0[16], s1[16];
#pragma unroll
    for (int r = 0; r < 16; ++r) { s0[r] = 0.f; s1[r] = 0.f; }

    const int i0 = chunk * ICH;
    for (int ig = 0; ig < ICH; ig += 4) {
        half8_t af[4], x0[4], x1[4];
        float c0[4], c1[4];
#pragma unroll
        for (int q = 0; q < 4; ++q) {
            const int i = i0 + ig + q;
            const _Float16* xb = Xh + (size_t)i * (B_ * L_);
            x0[q] = *(const half8_t*)(xb + kb * L_ + 8 * h2);
            x1[q] = *(const half8_t*)(xb + (32 + kb) * L_ + 8 * h2);
            af[q] = *(const half8_t*)(Wh + ((size_t)(i * J_ + j) * K_ + kb) * L_ + 8 * h2);
            const _Float16* cp = cbuf + ((size_t)j * I_ + i) * B_;
            c0[q] = (float)cp[kb];
            c1[q] = (float)cp[32 + kb];
        }
#pragma unroll
        for (int q = 0; q < 4; ++q) {
            f32x16 acc0 = __builtin_amdgcn_mfma_f32_32x32x16_f16(af[q], x0[q], fzero16(), 0, 0, 0);
            f32x16 acc1 = __builtin_amdgcn_mfma_f32_32x32x16_f16(af[q], x1[q], fzero16(), 0, 0, 0);
#pragma unroll
            for (int r = 0; r < 16; ++r) {
                s0[r] += c0[q] * acc0[r];
                s1[r] += c1[q] * acc1[r];
            }
        }
    }
    // coalesced flush: parts[chunk][j][k][b]
#pragma unroll
    for (int r = 0; r < 16; ++r) {
        const int k = (r & 3) + 8 * (r >> 2) + 4 * h2;
        _Float16* p = parts + (((size_t)chunk * J_ + j) * K_ + k) * B_;
        p[kb] = (_Float16)s0[r];
        p[32 + kb] = (_Float16)s1[r];
    }
}

// ---- reduce: block = j (grid 64), 512 threads: b = t&63, kg = t>>6, k = kg*4+q.
// Coalesced parts reads. Squash over k via tiny LDS.
// STEP0: s *= 1/64, wvz = v. STEP1: wvz += v. STEP2: out = v.
__global__ __launch_bounds__(512) void reduce_kernel(const _Float16* __restrict__ parts,
                                                     _Float16* __restrict__ wvz,
                                                     float* __restrict__ out,
                                                     int SCH, int STEP) {
    __shared__ float ssql[8][64];
    const int j = blockIdx.x;
    const int t = threadIdx.x;
    const int b = t & 63;
    const int kg = t >> 6;  // k = kg*4 + q, q in [0,4)

    float acc[4] = {0.f, 0.f, 0.f, 0.f};
    for (int ch = 0; ch < SCH; ++ch) {
        const _Float16* p = parts + (((size_t)ch * J_ + j) * K_ + kg * 4) * B_ + b;
#pragma unroll
        for (int q = 0; q < 4; ++q) acc[q] += (float)p[(size_t)q * B_];
    }
    if (STEP == 0) {
#pragma unroll
        for (int q = 0; q < 4; ++q) acc[q] *= (1.0f / 64.0f);
    }
    ssql[kg][b] = acc[0] * acc[0] + acc[1] * acc[1] + acc[2] * acc[2] + acc[3] * acc[3];
    __syncthreads();
    float sq = 0.f;
#pragma unroll
    for (int g = 0; g < 8; ++g) sq += ssql[g][b];
    const float scale = sq / (1.0f + sq) / sqrtf(sq + 1e-7f);

    if (STEP == 2) {
#pragma unroll
        for (int q = 0; q < 4; ++q)
            out[(size_t)b * N_ + j * K_ + kg * 4 + q] = acc[q] * scale;
    } else {
        // k = kg*4+q -> h2 = kg&1, r = q + 4*(kg>>1)
        _Float16* wp = wvz + ((size_t)(j * 2 + (kg & 1)) * B_ + b) * 16 + 4 * (kg >> 1);
#pragma unroll
        for (int q = 0; q < 4; ++q) {
            const float prev = (STEP == 0) ? 0.f : (float)wp[q];
            wp[q] = (_Float16)(prev + acc[q] * scale);
        }
    }
}

extern "C" void kernel_launch(void* const* d_in, const int* in_sizes, int n_in,
                              void* d_out, int out_size, void* d_ws, size_t ws_size,
                              hipStream_t stream) {
    const float* X = (const float*)d_in[0];  // [64][2048][16]
    const float* W = (const float*)d_in[1];  // [64][2048][32][16]
    float* out = (float*)d_out;              // [64][64][32]
    char* ws = (char*)d_ws;

    const size_t WH_BYTES = (size_t)I_ * J_ * K_ * L_ * 2;   // 134,217,728
    const size_t XH_BYTES = (size_t)I_ * B_ * L_ * 2;        //   4,194,304
    const size_t WVZ_BYTES = (size_t)J_ * 2 * B_ * 16 * 2;   //     262,144
    const size_t CB_BYTES = (size_t)J_ * I_ * B_ * 2;        //  16,777,216
    const size_t FIX = WH_BYTES + XH_BYTES + WVZ_BYTES + CB_BYTES;

    int SCH = 64;  // parts chunks; parts = SCH*N*B f16
    if (ws_size < FIX + (size_t)64 * N_ * B_ * 2) SCH = 32;
    if (ws_size < FIX + (size_t)32 * N_ * B_ * 2) SCH = 16;
    const int ICH = I_ / SCH;

    _Float16* Wh = (_Float16*)ws;
    _Float16* Xh = (_Float16*)(ws + WH_BYTES);
    _Float16* wvz = (_Float16*)(ws + WH_BYTES + XH_BYTES);
    _Float16* cbuf = (_Float16*)(ws + WH_BYTES + XH_BYTES + WVZ_BYTES);
    _Float16* parts = (_Float16*)(ws + FIX);

    cast_x_kernel<<<dim3((B_ * I_) / 256), dim3(256), 0, stream>>>(X, Xh);

    // r = 0: uniform c; fused fp32 read + cast + s0
    s0_cast_kernel<<<dim3(SCH * 8), dim3(512), 0, stream>>>(W, Wh, Xh, parts, SCH, ICH);
    reduce_kernel<<<dim3(J_), dim3(512), 0, stream>>>(parts, wvz, out, SCH, 0);

    // r = 1: c1 = softmax(v0 . u_hat); s1
    zsm2_kernel<<<dim3(I_ / 4), dim3(512), 0, stream>>>(Wh, Xh, wvz, cbuf);
    s_kernel<<<dim3(SCH * 8), dim3(512), 0, stream>>>(Wh, Xh, cbuf, parts, SCH, ICH);
    reduce_kernel<<<dim3(J_), dim3(512), 0, stream>>>(parts, wvz, out, SCH, 1);

    // r = 2: c2 = softmax((v0+v1) . u_hat); s2
    zsm2_kernel<<<dim3(I_ / 4), dim3(512), 0, stream>>>(Wh, Xh, wvz, cbuf);
    s_kernel<<<dim3(SCH * 8), dim3(512), 0, stream>>>(Wh, Xh, cbuf, parts, SCH, ICH);
    reduce_kernel<<<dim3(J_), dim3(512), 0, stream>>>(parts, wvz, out, SCH, 2);

    (void)in_sizes; (void)n_in; (void)out_size;
}

// Round 9
// 305.898 us; speedup vs baseline: 1.0050x; 1.0050x over previous
//
#include <hip/hip_runtime.h>

// CapsuleLayer dynamic routing, MI355X (gfx950).
// B=64, I=2048 (input caps), L=16 (in_dim), J=64 (out caps), K=32 (out dim).
// u_hat never materialized. Logits are linear in u_hat (b_r = (sum of prior v).u_hat).
// Per routing iteration r>0 (all passes: wave owns j, streams i — the proven shape):
//   zcalc: e[j][i][b] = exp(wv.u_hat) via MFMA. __launch_bounds__(512,6) caps VGPR
//          ~85 -> 6 waves/SIMD (R5-R8 showed the pass is latency-bound at 4/SIMD;
//          ILP batching was a null result, so TLP is the remaining lever).
//   dsum:  rD[i][b] = 1/sum_j e
//   s:     s partials = sum_i (e*rD)*u_hat -> parts[ch][j][k][b] coalesced flush
//          (R6 lesson: scattered 2B stores = 11x write-allocate amplification).
//   reduce: block=j, lane=b; squash; maintain wv fragments (f16, MFMA D-layout).
// r=0: s0_cast fuses the W fp32->f16 cast (single HBM read of W = the floor).
// MFMA 32x32x16 f16: D rows k = (r&3)+8*(r>>2)+4*(lane>>5), cols b = lane&31.

#define B_ 64
#define I_ 2048
#define L_ 16
#define J_ 64
#define K_ 32
#define N_ 2048  // J_*K_

typedef _Float16 half8_t __attribute__((ext_vector_type(8)));
typedef float f32x16 __attribute__((ext_vector_type(16)));
typedef float float4_t __attribute__((ext_vector_type(4)));

__device__ __forceinline__ f32x16 fzero16() {
    f32x16 z;
#pragma unroll
    for (int r = 0; r < 16; ++r) z[r] = 0.f;
    return z;
}

// ---- cast x: [b][i][l] fp32 -> Xh[i][b][l] f16
__global__ __launch_bounds__(256) void cast_x_kernel(const float* __restrict__ X,
                                                     _Float16* __restrict__ Xh) {
    unsigned tid = blockIdx.x * 256u + threadIdx.x;  // (i,b), b fastest
    unsigned b = tid & 63u;
    unsigned i = tid >> 6;
    const float4_t* src = (const float4_t*)(X + (size_t)(b * I_ + i) * L_);
    float4_t f0 = src[0], f1 = src[1], f2 = src[2], f3 = src[3];
    half8_t h0, h1;
#pragma unroll
    for (int e = 0; e < 4; ++e) {
        h0[e] = (_Float16)f0[e];
        h0[4 + e] = (_Float16)f1[e];
        h1[e] = (_Float16)f2[e];
        h1[4 + e] = (_Float16)f3[e];
    }
    _Float16* dst = Xh + (size_t)(i * B_ + b) * L_;
    *(half8_t*)dst = h0;
    *(half8_t*)(dst + 8) = h1;
}

// ---- r0 pass: uniform c (1/64 folded into reduce); fused W fp32 read + f16 cast.
// Grid: SCH*8 blocks x 512 threads; wave owns j = (blk&7)*8 + w, streams i-chunk.
__global__ __launch_bounds__(512) void s0_cast_kernel(const float* __restrict__ Wf,
                                                      _Float16* __restrict__ Wh_out,
                                                      const _Float16* __restrict__ Xh,
                                                      _Float16* __restrict__ parts,
                                                      int SCH, int ICH) {
    const int tid = threadIdx.x;
    const int w = tid >> 6;
    const int l = tid & 63;
    const int h2 = l >> 5;
    const int kb = l & 31;
    const int chunk = blockIdx.x >> 3;
    const int jq = blockIdx.x & 7;
    const int j = jq * 8 + w;

    float s0[16], s1[16];
#pragma unroll
    for (int r = 0; r < 16; ++r) { s0[r] = 0.f; s1[r] = 0.f; }

    const int i0 = chunk * ICH;
    for (int ii = 0; ii < ICH; ++ii) {
        const int i = i0 + ii;
        const _Float16* xb = Xh + (size_t)i * (B_ * L_);
        half8_t xf0 = *(const half8_t*)(xb + kb * L_ + 8 * h2);
        half8_t xf1 = *(const half8_t*)(xb + (32 + kb) * L_ + 8 * h2);
        const float4_t* wsrc =
            (const float4_t*)(Wf + ((size_t)(j * I_ + i) * K_ + kb) * L_ + 8 * h2);
        float4_t a0 = wsrc[0], a1 = wsrc[1];
        half8_t af;
#pragma unroll
        for (int e = 0; e < 4; ++e) {
            af[e] = (_Float16)a0[e];
            af[4 + e] = (_Float16)a1[e];
        }
        *(half8_t*)(Wh_out + ((size_t)(i * J_ + j) * K_ + kb) * L_ + 8 * h2) = af;
        f32x16 acc0 = __builtin_amdgcn_mfma_f32_32x32x16_f16(af, xf0, fzero16(), 0, 0, 0);
        f32x16 acc1 = __builtin_amdgcn_mfma_f32_32x32x16_f16(af, xf1, fzero16(), 0, 0, 0);
#pragma unroll
        for (int r = 0; r < 16; ++r) {
            s0[r] += acc0[r];
            s1[r] += acc1[r];
        }
    }
    // coalesced flush: parts[chunk][j][k][b]; per r, lanes write full 64B lines
#pragma unroll
    for (int r = 0; r < 16; ++r) {
        const int k = (r & 3) + 8 * (r >> 2) + 4 * h2;
        _Float16* p = parts + (((size_t)chunk * J_ + j) * K_ + k) * B_;
        p[kb] = (_Float16)s0[r];
        p[32 + kb] = (_Float16)s1[r];
    }
}

// ---- zcalc: e[j][i][b] = exp(z), z = wv . u_hat. Wave owns j, streams i.
// __launch_bounds__(512, 6): cap VGPR ~85 -> 6 waves/SIMD (TLP for latency hiding).
// wvz layout: [j][h2][b:64][r:16] f16 where k = (r&3) + 8*(r>>2) + 4*h2.
__global__ __launch_bounds__(512, 6) void zcalc_kernel(const _Float16* __restrict__ Wh,
                                                       const _Float16* __restrict__ Xh,
                                                       const _Float16* __restrict__ wvz,
                                                       _Float16* __restrict__ ebuf,
                                                       int SCH, int ICH) {
    const int tid = threadIdx.x;
    const int w = tid >> 6;
    const int l = tid & 63;
    const int h2 = l >> 5;
    const int kb = l & 31;
    const int chunk = blockIdx.x >> 3;
    const int jq = blockIdx.x & 7;
    const int j = jq * 8 + w;

    const _Float16* wp = wvz + ((size_t)(j * 2 + h2) * B_ + kb) * 16;
    const half8_t wv00 = *(const half8_t*)wp;          // batch kb,    regs 0-7
    const half8_t wv01 = *(const half8_t*)(wp + 8);    // batch kb,    regs 8-15
    const half8_t wv10 = *(const half8_t*)(wp + 512);  // batch kb+32, regs 0-7
    const half8_t wv11 = *(const half8_t*)(wp + 520);

    const int i0 = chunk * ICH;
    for (int ii = 0; ii < ICH; ++ii) {
        const int i = i0 + ii;
        const _Float16* xb = Xh + (size_t)i * (B_ * L_);
        half8_t xf0 = *(const half8_t*)(xb + kb * L_ + 8 * h2);
        half8_t xf1 = *(const half8_t*)(xb + (32 + kb) * L_ + 8 * h2);
        half8_t af = *(const half8_t*)(Wh + ((size_t)(i * J_ + j) * K_ + kb) * L_ + 8 * h2);
        // both MFMAs issued back-to-back (matrix pipe); contractions overlap on VALU
        f32x16 acc0 = __builtin_amdgcn_mfma_f32_32x32x16_f16(af, xf0, fzero16(), 0, 0, 0);
        f32x16 acc1 = __builtin_amdgcn_mfma_f32_32x32x16_f16(af, xf1, fzero16(), 0, 0, 0);
        // 4 independent partial chains per z (dep depth 4)
        float z0a = 0.f, z0b = 0.f, z0c = 0.f, z0d = 0.f;
        float z1a = 0.f, z1b = 0.f, z1c = 0.f, z1d = 0.f;
#pragma unroll
        for (int r = 0; r < 4; ++r) {
            z0a += acc0[r]      * (float)wv00[r];
            z0b += acc0[r + 4]  * (float)wv00[r + 4];
            z0c += acc0[r + 8]  * (float)wv01[r];
            z0d += acc0[r + 12] * (float)wv01[r + 4];
            z1a += acc1[r]      * (float)wv10[r];
            z1b += acc1[r + 4]  * (float)wv10[r + 4];
            z1c += acc1[r + 8]  * (float)wv11[r];
            z1d += acc1[r + 12] * (float)wv11[r + 4];
        }
        float z0 = (z0a + z0b) + (z0c + z0d);
        float z1 = (z1a + z1b) + (z1c + z1d);
        z0 += __shfl_xor(z0, 32, 64);  // combine disjoint k-halves
        z1 += __shfl_xor(z1, 32, 64);
        const float zf = fminf((l < 32) ? z0 : z1, 11.0f);  // |z|<~6; NaN insurance
        ebuf[((size_t)j * I_ + i) * B_ + l] = (_Float16)__expf(zf);
    }
}

// ---- dsum: rD[i][b] = 1 / sum_j e[j][i][b]. One wave per i, lane = b.
__global__ __launch_bounds__(256, 8) void dsum_kernel(const _Float16* __restrict__ ebuf,
                                                      float* __restrict__ rD) {
    const int w = threadIdx.x >> 6;
    const int l = threadIdx.x & 63;
    const int i = blockIdx.x * 4 + w;
    float p0 = 0.f, p1 = 0.f, p2 = 0.f, p3 = 0.f;
#pragma unroll
    for (int jq = 0; jq < 16; ++jq) {
        p0 += (float)ebuf[((size_t)(jq * 4 + 0) * I_ + i) * B_ + l];
        p1 += (float)ebuf[((size_t)(jq * 4 + 1) * I_ + i) * B_ + l];
        p2 += (float)ebuf[((size_t)(jq * 4 + 2) * I_ + i) * B_ + l];
        p3 += (float)ebuf[((size_t)(jq * 4 + 3) * I_ + i) * B_ + l];
    }
    rD[i * B_ + l] = 1.0f / ((p0 + p1) + (p2 + p3));
}

// ---- S: s partials over an i-chunk, weighted by c = e*rD. Simple stream.
__global__ __launch_bounds__(512) void s_kernel(const _Float16* __restrict__ Wh,
                                                const _Float16* __restrict__ Xh,
                                                const _Float16* __restrict__ ebuf,
                                                const float* __restrict__ rD,
                                                _Float16* __restrict__ parts,
                                                int SCH, int ICH) {
    const int tid = threadIdx.x;
    const int w = tid >> 6;
    const int l = tid & 63;
    const int h2 = l >> 5;
    const int kb = l & 31;
    const int chunk = blockIdx.x >> 3;
    const int jq = blockIdx.x & 7;
    const int j = jq * 8 + w;

    float s0[16], s1[16];
#pragma unroll
    for (int r = 0; r < 16; ++r) { s0[r] = 0.f; s1[r] = 0.f; }

    const int i0 = chunk * ICH;
    for (int ii = 0; ii < ICH; ++ii) {
        const int i = i0 + ii;
        const _Float16* xb = Xh + (size_t)i * (B_ * L_);
        half8_t xf0 = *(const half8_t*)(xb + kb * L_ + 8 * h2);
        half8_t xf1 = *(const half8_t*)(xb + (32 + kb) * L_ + 8 * h2);
        half8_t af = *(const half8_t*)(Wh + ((size_t)(i * J_ + j) * K_ + kb) * L_ + 8 * h2);
        const _Float16* ep = ebuf + ((size_t)j * I_ + i) * B_;
        const float c0 = (float)ep[kb] * rD[i * B_ + kb];
        const float c1 = (float)ep[32 + kb] * rD[i * B_ + 32 + kb];
        f32x16 acc0 = __builtin_amdgcn_mfma_f32_32x32x16_f16(af, xf0, fzero16(), 0, 0, 0);
        f32x16 acc1 = __builtin_amdgcn_mfma_f32_32x32x16_f16(af, xf1, fzero16(), 0, 0, 0);
#pragma unroll
        for (int r = 0; r < 16; ++r) {
            s0[r] += c0 * acc0[r];
            s1[r] += c1 * acc1[r];
        }
    }
    // coalesced flush: parts[chunk][j][k][b]
#pragma unroll
    for (int r = 0; r < 16; ++r) {
        const int k = (r & 3) + 8 * (r >> 2) + 4 * h2;
        _Float16* p = parts + (((size_t)chunk * J_ + j) * K_ + k) * B_;
        p[kb] = (_Float16)s0[r];
        p[32 + kb] = (_Float16)s1[r];
    }
}

// ---- reduce: block = j (grid 64), 512 threads: b = t&63, kg = t>>6, k = kg*4+q.
// Coalesced parts reads. Squash over k via tiny LDS.
// STEP0: s *= 1/64, wvz = v. STEP1: wvz += v. STEP2: out = v.
__global__ __launch_bounds__(512) void reduce_kernel(const _Float16* __restrict__ parts,
                                                     _Float16* __restrict__ wvz,
                                                     float* __restrict__ out,
                                                     int SCH, int STEP) {
    __shared__ float ssql[8][64];
    const int j = blockIdx.x;
    const int t = threadIdx.x;
    const int b = t & 63;
    const int kg = t >> 6;  // k = kg*4 + q, q in [0,4)

    float acc[4] = {0.f, 0.f, 0.f, 0.f};
    for (int ch = 0; ch < SCH; ++ch) {
        const _Float16* p = parts + (((size_t)ch * J_ + j) * K_ + kg * 4) * B_ + b;
#pragma unroll
        for (int q = 0; q < 4; ++q) acc[q] += (float)p[(size_t)q * B_];
    }
    if (STEP == 0) {
#pragma unroll
        for (int q = 0; q < 4; ++q) acc[q] *= (1.0f / 64.0f);
    }
    ssql[kg][b] = acc[0] * acc[0] + acc[1] * acc[1] + acc[2] * acc[2] + acc[3] * acc[3];
    __syncthreads();
    float sq = 0.f;
#pragma unroll
    for (int g = 0; g < 8; ++g) sq += ssql[g][b];
    const float scale = sq / (1.0f + sq) / sqrtf(sq + 1e-7f);

    if (STEP == 2) {
#pragma unroll
        for (int q = 0; q < 4; ++q)
            out[(size_t)b * N_ + j * K_ + kg * 4 + q] = acc[q] * scale;
    } else {
        // k = kg*4+q -> h2 = kg&1, r = q + 4*(kg>>1)
        _Float16* wp = wvz + ((size_t)(j * 2 + (kg & 1)) * B_ + b) * 16 + 4 * (kg >> 1);
#pragma unroll
        for (int q = 0; q < 4; ++q) {
            const float prev = (STEP == 0) ? 0.f : (float)wp[q];
            wp[q] = (_Float16)(prev + acc[q] * scale);
        }
    }
}

extern "C" void kernel_launch(void* const* d_in, const int* in_sizes, int n_in,
                              void* d_out, int out_size, void* d_ws, size_t ws_size,
                              hipStream_t stream) {
    const float* X = (const float*)d_in[0];  // [64][2048][16]
    const float* W = (const float*)d_in[1];  // [64][2048][32][16]
    float* out = (float*)d_out;              // [64][64][32]
    char* ws = (char*)d_ws;

    const size_t WH_BYTES = (size_t)I_ * J_ * K_ * L_ * 2;   // 134,217,728
    const size_t XH_BYTES = (size_t)I_ * B_ * L_ * 2;        //   4,194,304
    const size_t WVZ_BYTES = (size_t)J_ * 2 * B_ * 16 * 2;   //     262,144
    const size_t EB_BYTES = (size_t)J_ * I_ * B_ * 2;        //  16,777,216
    const size_t RD_BYTES = (size_t)I_ * B_ * 4;             //     524,288
    const size_t FIX = WH_BYTES + XH_BYTES + WVZ_BYTES + EB_BYTES + RD_BYTES;

    int SCH = 64;  // parts chunks; parts = SCH*N*B f16
    if (ws_size < FIX + (size_t)64 * N_ * B_ * 2) SCH = 32;
    if (ws_size < FIX + (size_t)32 * N_ * B_ * 2) SCH = 16;
    const int ICH = I_ / SCH;

    _Float16* Wh = (_Float16*)ws;
    _Float16* Xh = (_Float16*)(ws + WH_BYTES);
    _Float16* wvz = (_Float16*)(ws + WH_BYTES + XH_BYTES);
    _Float16* ebuf = (_Float16*)(ws + WH_BYTES + XH_BYTES + WVZ_BYTES);
    float* rD = (float*)(ws + WH_BYTES + XH_BYTES + WVZ_BYTES + EB_BYTES);
    _Float16* parts = (_Float16*)(ws + FIX);

    cast_x_kernel<<<dim3((B_ * I_) / 256), dim3(256), 0, stream>>>(X, Xh);

    // r = 0: uniform c; fused fp32 read + cast + s0
    s0_cast_kernel<<<dim3(SCH * 8), dim3(512), 0, stream>>>(W, Wh, Xh, parts, SCH, ICH);
    reduce_kernel<<<dim3(J_), dim3(512), 0, stream>>>(parts, wvz, out, SCH, 0);

    // r = 1: e = exp(v0 . u_hat); rD; s1
    zcalc_kernel<<<dim3(SCH * 8), dim3(512), 0, stream>>>(Wh, Xh, wvz, ebuf, SCH, ICH);
    dsum_kernel<<<dim3(I_ / 4), dim3(256), 0, stream>>>(ebuf, rD);
    s_kernel<<<dim3(SCH * 8), dim3(512), 0, stream>>>(Wh, Xh, ebuf, rD, parts, SCH, ICH);
    reduce_kernel<<<dim3(J_), dim3(512), 0, stream>>>(parts, wvz, out, SCH, 1);

    // r = 2: e = exp((v0+v1) . u_hat); rD; s2
    zcalc_kernel<<<dim3(SCH * 8), dim3(512), 0, stream>>>(Wh, Xh, wvz, ebuf, SCH, ICH);
    dsum_kernel<<<dim3(I_ / 4), dim3(256), 0, stream>>>(ebuf, rD);
    s_kernel<<<dim3(SCH * 8), dim3(512), 0, stream>>>(Wh, Xh, ebuf, rD, parts, SCH, ICH);
    reduce_kernel<<<dim3(J_), dim3(512), 0, stream>>>(parts, wvz, out, SCH, 2);

    (void)in_sizes; (void)n_in; (void)out_size;
}

// Round 10
// 292.422 us; speedup vs baseline: 1.0513x; 1.0461x over previous
//
#include <hip/hip_runtime.h>

// CapsuleLayer dynamic routing, MI355X (gfx950).
// B=64, I=2048 (input caps), L=16 (in_dim), J=64 (out caps), K=32 (out dim).
// u_hat never materialized. Logits are linear in u_hat (b_r = (sum of prior v).u_hat).
// Per routing iteration r>0:
//   zcalc: e[j][i][b] = exp(wv.u_hat) via MFMA; ALSO accumulates the softmax
//          denominator D[i][b] (8-i tiles: LDS reduce over the block's 8 j, then
//          one f32 atomicAdd per (block,i,b) — replaces the dsum kernel).
//   s:     s partials = sum_i e*rcp(D)*u_hat -> parts[ch][j][k][b] coalesced
//          (R6 lesson: scattered 2B stores = 11x write-allocate amplification).
//   reduce: block=j, lane=b; squash; maintain wv frags; zeros D for next iter.
// r=0: s0_cast fuses the W fp32->f16 cast (single HBM read of W = the floor).
// MFMA 32x32x16 f16: D rows k = (r&3)+8*(r>>2)+4*(lane>>5), cols b = lane&31.
// Byte ledger ~1.4 GB @ ~6 TB/s + 9 launches => this structure is near its
// practical memory roofline; this round trims launches and redundant traffic.

#define B_ 64
#define I_ 2048
#define L_ 16
#define J_ 64
#define K_ 32
#define N_ 2048  // J_*K_

typedef _Float16 half8_t __attribute__((ext_vector_type(8)));
typedef float f32x16 __attribute__((ext_vector_type(16)));
typedef float float4_t __attribute__((ext_vector_type(4)));

__device__ __forceinline__ f32x16 fzero16() {
    f32x16 z;
#pragma unroll
    for (int r = 0; r < 16; ++r) z[r] = 0.f;
    return z;
}

// ---- cast x: [b][i][l] fp32 -> Xh[i][b][l] f16
__global__ __launch_bounds__(256) void cast_x_kernel(const float* __restrict__ X,
                                                     _Float16* __restrict__ Xh) {
    unsigned tid = blockIdx.x * 256u + threadIdx.x;  // (i,b), b fastest
    unsigned b = tid & 63u;
    unsigned i = tid >> 6;
    const float4_t* src = (const float4_t*)(X + (size_t)(b * I_ + i) * L_);
    float4_t f0 = src[0], f1 = src[1], f2 = src[2], f3 = src[3];
    half8_t h0, h1;
#pragma unroll
    for (int e = 0; e < 4; ++e) {
        h0[e] = (_Float16)f0[e];
        h0[4 + e] = (_Float16)f1[e];
        h1[e] = (_Float16)f2[e];
        h1[4 + e] = (_Float16)f3[e];
    }
    _Float16* dst = Xh + (size_t)(i * B_ + b) * L_;
    *(half8_t*)dst = h0;
    *(half8_t*)(dst + 8) = h1;
}

// ---- r0 pass: uniform c (1/64 folded into reduce); fused W fp32 read + f16 cast.
// Grid: SCH*8 blocks x 512 threads; wave owns j = (blk&7)*8 + w, streams i-chunk.
__global__ __launch_bounds__(512) void s0_cast_kernel(const float* __restrict__ Wf,
                                                      _Float16* __restrict__ Wh_out,
                                                      const _Float16* __restrict__ Xh,
                                                      _Float16* __restrict__ parts,
                                                      int SCH, int ICH) {
    const int tid = threadIdx.x;
    const int w = tid >> 6;
    const int l = tid & 63;
    const int h2 = l >> 5;
    const int kb = l & 31;
    const int chunk = blockIdx.x >> 3;
    const int jq = blockIdx.x & 7;
    const int j = jq * 8 + w;

    float s0[16], s1[16];
#pragma unroll
    for (int r = 0; r < 16; ++r) { s0[r] = 0.f; s1[r] = 0.f; }

    const int i0 = chunk * ICH;
    for (int ii = 0; ii < ICH; ++ii) {
        const int i = i0 + ii;
        const _Float16* xb = Xh + (size_t)i * (B_ * L_);
        half8_t xf0 = *(const half8_t*)(xb + kb * L_ + 8 * h2);
        half8_t xf1 = *(const half8_t*)(xb + (32 + kb) * L_ + 8 * h2);
        const float4_t* wsrc =
            (const float4_t*)(Wf + ((size_t)(j * I_ + i) * K_ + kb) * L_ + 8 * h2);
        float4_t a0 = wsrc[0], a1 = wsrc[1];
        half8_t af;
#pragma unroll
        for (int e = 0; e < 4; ++e) {
            af[e] = (_Float16)a0[e];
            af[4 + e] = (_Float16)a1[e];
        }
        *(half8_t*)(Wh_out + ((size_t)(i * J_ + j) * K_ + kb) * L_ + 8 * h2) = af;
        f32x16 acc0 = __builtin_amdgcn_mfma_f32_32x32x16_f16(af, xf0, fzero16(), 0, 0, 0);
        f32x16 acc1 = __builtin_amdgcn_mfma_f32_32x32x16_f16(af, xf1, fzero16(), 0, 0, 0);
#pragma unroll
        for (int r = 0; r < 16; ++r) {
            s0[r] += acc0[r];
            s1[r] += acc1[r];
        }
    }
    // coalesced flush: parts[chunk][j][k][b]; per r, lanes write full 64B lines
#pragma unroll
    for (int r = 0; r < 16; ++r) {
        const int k = (r & 3) + 8 * (r >> 2) + 4 * h2;
        _Float16* p = parts + (((size_t)chunk * J_ + j) * K_ + k) * B_;
        p[kb] = (_Float16)s0[r];
        p[32 + kb] = (_Float16)s1[r];
    }
}

// ---- zcalc: e[j][i][b] = exp(z), z = wv . u_hat; accumulates D[i][b] = sum_j e.
// Wave owns j, streams i in 8-i tiles. After each tile: LDS reduce over the
// block's 8 j + one atomicAdd per (i,b). D pre-zeroed by the preceding reduce.
// wvz layout: [j][h2][b:64][r:16] f16 where k = (r&3) + 8*(r>>2) + 4*h2.
__global__ __launch_bounds__(512) void zcalc_kernel(const _Float16* __restrict__ Wh,
                                                    const _Float16* __restrict__ Xh,
                                                    const _Float16* __restrict__ wvz,
                                                    _Float16* __restrict__ ebuf,
                                                    float* __restrict__ D,
                                                    int SCH, int ICH) {
    __shared__ float es[8][8][64];  // [wave(j)][i_local][b] = 16 KB
    const int tid = threadIdx.x;
    const int w = tid >> 6;
    const int l = tid & 63;
    const int h2 = l >> 5;
    const int kb = l & 31;
    const int chunk = blockIdx.x >> 3;
    const int jq = blockIdx.x & 7;
    const int j = jq * 8 + w;

    const _Float16* wp = wvz + ((size_t)(j * 2 + h2) * B_ + kb) * 16;
    const half8_t wv00 = *(const half8_t*)wp;          // batch kb,    regs 0-7
    const half8_t wv01 = *(const half8_t*)(wp + 8);    // batch kb,    regs 8-15
    const half8_t wv10 = *(const half8_t*)(wp + 512);  // batch kb+32, regs 0-7
    const half8_t wv11 = *(const half8_t*)(wp + 520);

    const int i0 = chunk * ICH;
    for (int it = 0; it < ICH; it += 8) {
#pragma unroll
        for (int q = 0; q < 8; ++q) {
            const int i = i0 + it + q;
            const _Float16* xb = Xh + (size_t)i * (B_ * L_);
            half8_t xf0 = *(const half8_t*)(xb + kb * L_ + 8 * h2);
            half8_t xf1 = *(const half8_t*)(xb + (32 + kb) * L_ + 8 * h2);
            half8_t af = *(const half8_t*)(Wh + ((size_t)(i * J_ + j) * K_ + kb) * L_ + 8 * h2);
            f32x16 acc0 = __builtin_amdgcn_mfma_f32_32x32x16_f16(af, xf0, fzero16(), 0, 0, 0);
            f32x16 acc1 = __builtin_amdgcn_mfma_f32_32x32x16_f16(af, xf1, fzero16(), 0, 0, 0);
            // 4 independent partial chains per z (dep depth 4)
            float z0a = 0.f, z0b = 0.f, z0c = 0.f, z0d = 0.f;
            float z1a = 0.f, z1b = 0.f, z1c = 0.f, z1d = 0.f;
#pragma unroll
            for (int r = 0; r < 4; ++r) {
                z0a += acc0[r]      * (float)wv00[r];
                z0b += acc0[r + 4]  * (float)wv00[r + 4];
                z0c += acc0[r + 8]  * (float)wv01[r];
                z0d += acc0[r + 12] * (float)wv01[r + 4];
                z1a += acc1[r]      * (float)wv10[r];
                z1b += acc1[r + 4]  * (float)wv10[r + 4];
                z1c += acc1[r + 8]  * (float)wv11[r];
                z1d += acc1[r + 12] * (float)wv11[r + 4];
            }
            float z0 = (z0a + z0b) + (z0c + z0d);
            float z1 = (z1a + z1b) + (z1c + z1d);
            z0 += __shfl_xor(z0, 32, 64);  // combine disjoint k-halves
            z1 += __shfl_xor(z1, 32, 64);
            const float zf = fminf((l < 32) ? z0 : z1, 11.0f);  // |z|<~6; NaN insurance
            const float ev = __expf(zf);
            ebuf[((size_t)j * I_ + i) * B_ + l] = (_Float16)ev;
            es[w][q][l] = ev;
        }
        __syncthreads();
        // wave w reduces i_local = w over the block's 8 j, one atomicAdd per (i,b)
        {
            float p0 = es[0][w][l] + es[1][w][l];
            float p1 = es[2][w][l] + es[3][w][l];
            float p2 = es[4][w][l] + es[5][w][l];
            float p3 = es[6][w][l] + es[7][w][l];
            atomicAdd(&D[(size_t)(i0 + it + w) * B_ + l], (p0 + p1) + (p2 + p3));
        }
        __syncthreads();
    }
}

// ---- S: s partials over an i-chunk, weighted by c = e * rcp(D). Simple stream.
__global__ __launch_bounds__(512) void s_kernel(const _Float16* __restrict__ Wh,
                                                const _Float16* __restrict__ Xh,
                                                const _Float16* __restrict__ ebuf,
                                                const float* __restrict__ D,
                                                _Float16* __restrict__ parts,
                                                int SCH, int ICH) {
    const int tid = threadIdx.x;
    const int w = tid >> 6;
    const int l = tid & 63;
    const int h2 = l >> 5;
    const int kb = l & 31;
    const int chunk = blockIdx.x >> 3;
    const int jq = blockIdx.x & 7;
    const int j = jq * 8 + w;

    float s0[16], s1[16];
#pragma unroll
    for (int r = 0; r < 16; ++r) { s0[r] = 0.f; s1[r] = 0.f; }

    const int i0 = chunk * ICH;
    for (int ii = 0; ii < ICH; ++ii) {
        const int i = i0 + ii;
        const _Float16* xb = Xh + (size_t)i * (B_ * L_);
        half8_t xf0 = *(const half8_t*)(xb + kb * L_ + 8 * h2);
        half8_t xf1 = *(const half8_t*)(xb + (32 + kb) * L_ + 8 * h2);
        half8_t af = *(const half8_t*)(Wh + ((size_t)(i * J_ + j) * K_ + kb) * L_ + 8 * h2);
        const _Float16* ep = ebuf + ((size_t)j * I_ + i) * B_;
        const float c0 = (float)ep[kb] * __builtin_amdgcn_rcpf(D[(size_t)i * B_ + kb]);
        const float c1 = (float)ep[32 + kb] * __builtin_amdgcn_rcpf(D[(size_t)i * B_ + 32 + kb]);
        f32x16 acc0 = __builtin_amdgcn_mfma_f32_32x32x16_f16(af, xf0, fzero16(), 0, 0, 0);
        f32x16 acc1 = __builtin_amdgcn_mfma_f32_32x32x16_f16(af, xf1, fzero16(), 0, 0, 0);
#pragma unroll
        for (int r = 0; r < 16; ++r) {
            s0[r] += c0 * acc0[r];
            s1[r] += c1 * acc1[r];
        }
    }
    // coalesced flush: parts[chunk][j][k][b]
#pragma unroll
    for (int r = 0; r < 16; ++r) {
        const int k = (r & 3) + 8 * (r >> 2) + 4 * h2;
        _Float16* p = parts + (((size_t)chunk * J_ + j) * K_ + k) * B_;
        p[kb] = (_Float16)s0[r];
        p[32 + kb] = (_Float16)s1[r];
    }
}

// ---- reduce: block = j (grid 64), 512 threads: b = t&63, kg = t>>6, k = kg*4+q.
// Coalesced parts reads. Squash over k via tiny LDS. Zeros D for the next
// iteration when STEP < 2 (runs before the zcalc that atomically accumulates).
// STEP0: s *= 1/64, wvz = v. STEP1: wvz += v. STEP2: out = v.
__global__ __launch_bounds__(512) void reduce_kernel(const _Float16* __restrict__ parts,
                                                     _Float16* __restrict__ wvz,
                                                     float* __restrict__ out,
                                                     float* __restrict__ D,
                                                     int SCH, int STEP) {
    __shared__ float ssql[8][64];
    const int j = blockIdx.x;
    const int t = threadIdx.x;
    const int b = t & 63;
    const int kg = t >> 6;  // k = kg*4 + q, q in [0,4)

    if (STEP < 2) {
        // zero D: 131072 floats over 64 blocks x 512 threads = float4 per thread
        float4_t zz = {0.f, 0.f, 0.f, 0.f};
        ((float4_t*)D)[(size_t)j * 512 + t] = zz;
    }

    float acc[4] = {0.f, 0.f, 0.f, 0.f};
    for (int ch = 0; ch < SCH; ++ch) {
        const _Float16* p = parts + (((size_t)ch * J_ + j) * K_ + kg * 4) * B_ + b;
#pragma unroll
        for (int q = 0; q < 4; ++q) acc[q] += (float)p[(size_t)q * B_];
    }
    if (STEP == 0) {
#pragma unroll
        for (int q = 0; q < 4; ++q) acc[q] *= (1.0f / 64.0f);
    }
    ssql[kg][b] = acc[0] * acc[0] + acc[1] * acc[1] + acc[2] * acc[2] + acc[3] * acc[3];
    __syncthreads();
    float sq = 0.f;
#pragma unroll
    for (int g = 0; g < 8; ++g) sq += ssql[g][b];
    const float scale = sq / (1.0f + sq) / sqrtf(sq + 1e-7f);

    if (STEP == 2) {
#pragma unroll
        for (int q = 0; q < 4; ++q)
            out[(size_t)b * N_ + j * K_ + kg * 4 + q] = acc[q] * scale;
    } else {
        // k = kg*4+q -> h2 = kg&1, r = q + 4*(kg>>1)
        _Float16* wp = wvz + ((size_t)(j * 2 + (kg & 1)) * B_ + b) * 16 + 4 * (kg >> 1);
#pragma unroll
        for (int q = 0; q < 4; ++q) {
            const float prev = (STEP == 0) ? 0.f : (float)wp[q];
            wp[q] = (_Float16)(prev + acc[q] * scale);
        }
    }
}

extern "C" void kernel_launch(void* const* d_in, const int* in_sizes, int n_in,
                              void* d_out, int out_size, void* d_ws, size_t ws_size,
                              hipStream_t stream) {
    const float* X = (const float*)d_in[0];  // [64][2048][16]
    const float* W = (const float*)d_in[1];  // [64][2048][32][16]
    float* out = (float*)d_out;              // [64][64][32]
    char* ws = (char*)d_ws;

    const size_t WH_BYTES = (size_t)I_ * J_ * K_ * L_ * 2;   // 134,217,728
    const size_t XH_BYTES = (size_t)I_ * B_ * L_ * 2;        //   4,194,304
    const size_t WVZ_BYTES = (size_t)J_ * 2 * B_ * 16 * 2;   //     262,144
    const size_t EB_BYTES = (size_t)J_ * I_ * B_ * 2;        //  16,777,216
    const size_t D_BYTES = (size_t)I_ * B_ * 4;              //     524,288
    const size_t FIX = WH_BYTES + XH_BYTES + WVZ_BYTES + EB_BYTES + D_BYTES;

    int SCH = 64;  // parts chunks; parts = SCH*N*B f16
    if (ws_size < FIX + (size_t)64 * N_ * B_ * 2) SCH = 32;
    if (ws_size < FIX + (size_t)32 * N_ * B_ * 2) SCH = 16;
    const int ICH = I_ / SCH;

    _Float16* Wh = (_Float16*)ws;
    _Float16* Xh = (_Float16*)(ws + WH_BYTES);
    _Float16* wvz = (_Float16*)(ws + WH_BYTES + XH_BYTES);
    _Float16* ebuf = (_Float16*)(ws + WH_BYTES + XH_BYTES + WVZ_BYTES);
    float* D = (float*)(ws + WH_BYTES + XH_BYTES + WVZ_BYTES + EB_BYTES);
    _Float16* parts = (_Float16*)(ws + FIX);

    cast_x_kernel<<<dim3((B_ * I_) / 256), dim3(256), 0, stream>>>(X, Xh);

    // r = 0: uniform c; fused fp32 read + cast + s0
    s0_cast_kernel<<<dim3(SCH * 8), dim3(512), 0, stream>>>(W, Wh, Xh, parts, SCH, ICH);
    reduce_kernel<<<dim3(J_), dim3(512), 0, stream>>>(parts, wvz, out, D, SCH, 0);

    // r = 1: e = exp(v0 . u_hat), D accumulated in-kernel; s1
    zcalc_kernel<<<dim3(SCH * 8), dim3(512), 0, stream>>>(Wh, Xh, wvz, ebuf, D, SCH, ICH);
    s_kernel<<<dim3(SCH * 8), dim3(512), 0, stream>>>(Wh, Xh, ebuf, D, parts, SCH, ICH);
    reduce_kernel<<<dim3(J_), dim3(512), 0, stream>>>(parts, wvz, out, D, SCH, 1);

    // r = 2: e = exp((v0+v1) . u_hat), D accumulated in-kernel; s2
    zcalc_kernel<<<dim3(SCH * 8), dim3(512), 0, stream>>>(Wh, Xh, wvz, ebuf, D, SCH, ICH);
    s_kernel<<<dim3(SCH * 8), dim3(512), 0, stream>>>(Wh, Xh, ebuf, D, parts, SCH, ICH);
    reduce_kernel<<<dim3(J_), dim3(512), 0, stream>>>(parts, wvz, out, D, SCH, 2);

    (void)in_sizes; (void)n_in; (void)out_size;
}

// Round 11
// 247.029 us; speedup vs baseline: 1.2445x; 1.1838x over previous
//
#include <hip/hip_runtime.h>

// CapsuleLayer dynamic routing, MI355X (gfx950).
// B=64, I=2048 (input caps), L=16 (in_dim), J=64 (out caps), K=32 (out dim).
// u_hat never materialized. Logits are linear in u_hat (b_r = (sum of prior v).u_hat).
// Structure (5 W-streams, algebraically forced by the per-iteration global softmax):
//   s0_cast: read W fp32 once (nt hint), cast->Wh f16, accumulate s0 (uniform c).
//   zcalc:   e[j][i][b] = exp(wv.u_hat) via MFMA; accumulates softmax denom D[i][b]
//            in-kernel (8-i LDS tile reduce + one f32 atomicAdd per (i,b)).
//   s:       s partials = sum_i e*rcp(D)*u_hat -> parts[ch][j][k][b] coalesced.
//   reduce:  block=j, lane=b; squash; maintain wv frags; zero D for next iter.
// Key HW finding (R5-R10): L3 residency gives NO bandwidth uplift on these
// streams -- every pass pays its bytes at ~5-6 TB/s. Floor = total bytes.
// R11: SCH=32 (halve parts traffic), nt-load the 536 MB W fp32 stream.
// MFMA 32x32x16 f16: D rows k = (r&3)+8*(r>>2)+4*(lane>>5), cols b = lane&31.

#define B_ 64
#define I_ 2048
#define L_ 16
#define J_ 64
#define K_ 32
#define N_ 2048  // J_*K_
#define SCH_ 32  // partial-sum chunks; grid = SCH_*8 = 256 blocks (1/CU)
#define ICH_ (I_ / SCH_)

typedef _Float16 half8_t __attribute__((ext_vector_type(8)));
typedef float f32x16 __attribute__((ext_vector_type(16)));
typedef float float4_t __attribute__((ext_vector_type(4)));

__device__ __forceinline__ f32x16 fzero16() {
    f32x16 z;
#pragma unroll
    for (int r = 0; r < 16; ++r) z[r] = 0.f;
    return z;
}

// ---- cast x: [b][i][l] fp32 -> Xh[i][b][l] f16
__global__ __launch_bounds__(256) void cast_x_kernel(const float* __restrict__ X,
                                                     _Float16* __restrict__ Xh) {
    unsigned tid = blockIdx.x * 256u + threadIdx.x;  // (i,b), b fastest
    unsigned b = tid & 63u;
    unsigned i = tid >> 6;
    const float4_t* src = (const float4_t*)(X + (size_t)(b * I_ + i) * L_);
    float4_t f0 = src[0], f1 = src[1], f2 = src[2], f3 = src[3];
    half8_t h0, h1;
#pragma unroll
    for (int e = 0; e < 4; ++e) {
        h0[e] = (_Float16)f0[e];
        h0[4 + e] = (_Float16)f1[e];
        h1[e] = (_Float16)f2[e];
        h1[4 + e] = (_Float16)f3[e];
    }
    _Float16* dst = Xh + (size_t)(i * B_ + b) * L_;
    *(half8_t*)dst = h0;
    *(half8_t*)(dst + 8) = h1;
}

// ---- r0 pass: uniform c (1/64 folded into reduce); fused W fp32 read + f16 cast.
// Grid: SCH_*8 blocks x 512 threads; wave owns j = (blk&7)*8 + w, streams i-chunk.
__global__ __launch_bounds__(512) void s0_cast_kernel(const float* __restrict__ Wf,
                                                      _Float16* __restrict__ Wh_out,
                                                      const _Float16* __restrict__ Xh,
                                                      _Float16* __restrict__ parts) {
    const int tid = threadIdx.x;
    const int w = tid >> 6;
    const int l = tid & 63;
    const int h2 = l >> 5;
    const int kb = l & 31;
    const int chunk = blockIdx.x >> 3;
    const int jq = blockIdx.x & 7;
    const int j = jq * 8 + w;

    float s0[16], s1[16];
#pragma unroll
    for (int r = 0; r < 16; ++r) { s0[r] = 0.f; s1[r] = 0.f; }

    const int i0 = chunk * ICH_;
    for (int ii = 0; ii < ICH_; ++ii) {
        const int i = i0 + ii;
        const _Float16* xb = Xh + (size_t)i * (B_ * L_);
        half8_t xf0 = *(const half8_t*)(xb + kb * L_ + 8 * h2);
        half8_t xf1 = *(const half8_t*)(xb + (32 + kb) * L_ + 8 * h2);
        // nt: W fp32 is read exactly once across the whole problem -- keep it
        // from evicting Wh/parts write streams out of L2/L3.
        const float4_t* wsrc =
            (const float4_t*)(Wf + ((size_t)(j * I_ + i) * K_ + kb) * L_ + 8 * h2);
        float4_t a0 = __builtin_nontemporal_load(wsrc);
        float4_t a1 = __builtin_nontemporal_load(wsrc + 1);
        half8_t af;
#pragma unroll
        for (int e = 0; e < 4; ++e) {
            af[e] = (_Float16)a0[e];
            af[4 + e] = (_Float16)a1[e];
        }
        *(half8_t*)(Wh_out + ((size_t)(i * J_ + j) * K_ + kb) * L_ + 8 * h2) = af;
        f32x16 acc0 = __builtin_amdgcn_mfma_f32_32x32x16_f16(af, xf0, fzero16(), 0, 0, 0);
        f32x16 acc1 = __builtin_amdgcn_mfma_f32_32x32x16_f16(af, xf1, fzero16(), 0, 0, 0);
#pragma unroll
        for (int r = 0; r < 16; ++r) {
            s0[r] += acc0[r];
            s1[r] += acc1[r];
        }
    }
    // coalesced flush: parts[chunk][j][k][b]; per r, lanes write full 64B lines
#pragma unroll
    for (int r = 0; r < 16; ++r) {
        const int k = (r & 3) + 8 * (r >> 2) + 4 * h2;
        _Float16* p = parts + (((size_t)chunk * J_ + j) * K_ + k) * B_;
        p[kb] = (_Float16)s0[r];
        p[32 + kb] = (_Float16)s1[r];
    }
}

// ---- zcalc: e[j][i][b] = exp(z), z = wv . u_hat; accumulates D[i][b] = sum_j e.
// Wave owns j, streams i in 8-i tiles. After each tile: LDS reduce over the
// block's 8 j + one atomicAdd per (i,b). D pre-zeroed by the preceding reduce.
// wvz layout: [j][h2][b:64][r:16] f16 where k = (r&3) + 8*(r>>2) + 4*h2.
__global__ __launch_bounds__(512) void zcalc_kernel(const _Float16* __restrict__ Wh,
                                                    const _Float16* __restrict__ Xh,
                                                    const _Float16* __restrict__ wvz,
                                                    _Float16* __restrict__ ebuf,
                                                    float* __restrict__ D) {
    __shared__ float es[8][8][64];  // [wave(j)][i_local][b] = 16 KB
    const int tid = threadIdx.x;
    const int w = tid >> 6;
    const int l = tid & 63;
    const int h2 = l >> 5;
    const int kb = l & 31;
    const int chunk = blockIdx.x >> 3;
    const int jq = blockIdx.x & 7;
    const int j = jq * 8 + w;

    const _Float16* wp = wvz + ((size_t)(j * 2 + h2) * B_ + kb) * 16;
    const half8_t wv00 = *(const half8_t*)wp;          // batch kb,    regs 0-7
    const half8_t wv01 = *(const half8_t*)(wp + 8);    // batch kb,    regs 8-15
    const half8_t wv10 = *(const half8_t*)(wp + 512);  // batch kb+32, regs 0-7
    const half8_t wv11 = *(const half8_t*)(wp + 520);

    const int i0 = chunk * ICH_;
    for (int it = 0; it < ICH_; it += 8) {
#pragma unroll
        for (int q = 0; q < 8; ++q) {
            const int i = i0 + it + q;
            const _Float16* xb = Xh + (size_t)i * (B_ * L_);
            half8_t xf0 = *(const half8_t*)(xb + kb * L_ + 8 * h2);
            half8_t xf1 = *(const half8_t*)(xb + (32 + kb) * L_ + 8 * h2);
            half8_t af = *(const half8_t*)(Wh + ((size_t)(i * J_ + j) * K_ + kb) * L_ + 8 * h2);
            f32x16 acc0 = __builtin_amdgcn_mfma_f32_32x32x16_f16(af, xf0, fzero16(), 0, 0, 0);
            f32x16 acc1 = __builtin_amdgcn_mfma_f32_32x32x16_f16(af, xf1, fzero16(), 0, 0, 0);
            // 4 independent partial chains per z (dep depth 4)
            float z0a = 0.f, z0b = 0.f, z0c = 0.f, z0d = 0.f;
            float z1a = 0.f, z1b = 0.f, z1c = 0.f, z1d = 0.f;
#pragma unroll
            for (int r = 0; r < 4; ++r) {
                z0a += acc0[r]      * (float)wv00[r];
                z0b += acc0[r + 4]  * (float)wv00[r + 4];
                z0c += acc0[r + 8]  * (float)wv01[r];
                z0d += acc0[r + 12] * (float)wv01[r + 4];
                z1a += acc1[r]      * (float)wv10[r];
                z1b += acc1[r + 4]  * (float)wv10[r + 4];
                z1c += acc1[r + 8]  * (float)wv11[r];
                z1d += acc1[r + 12] * (float)wv11[r + 4];
            }
            float z0 = (z0a + z0b) + (z0c + z0d);
            float z1 = (z1a + z1b) + (z1c + z1d);
            z0 += __shfl_xor(z0, 32, 64);  // combine disjoint k-halves
            z1 += __shfl_xor(z1, 32, 64);
            const float zf = fminf((l < 32) ? z0 : z1, 11.0f);  // |z|<~6; NaN insurance
            const float ev = __expf(zf);
            ebuf[((size_t)j * I_ + i) * B_ + l] = (_Float16)ev;
            es[w][q][l] = ev;
        }
        __syncthreads();
        // wave w reduces i_local = w over the block's 8 j, one atomicAdd per (i,b)
        {
            float p0 = es[0][w][l] + es[1][w][l];
            float p1 = es[2][w][l] + es[3][w][l];
            float p2 = es[4][w][l] + es[5][w][l];
            float p3 = es[6][w][l] + es[7][w][l];
            atomicAdd(&D[(size_t)(i0 + it + w) * B_ + l], (p0 + p1) + (p2 + p3));
        }
        __syncthreads();
    }
}

// ---- S: s partials over an i-chunk, weighted by c = e * rcp(D). Simple stream.
__global__ __launch_bounds__(512) void s_kernel(const _Float16* __restrict__ Wh,
                                                const _Float16* __restrict__ Xh,
                                                const _Float16* __restrict__ ebuf,
                                                const float* __restrict__ D,
                                                _Float16* __restrict__ parts) {
    const int tid = threadIdx.x;
    const int w = tid >> 6;
    const int l = tid & 63;
    const int h2 = l >> 5;
    const int kb = l & 31;
    const int chunk = blockIdx.x >> 3;
    const int jq = blockIdx.x & 7;
    const int j = jq * 8 + w;

    float s0[16], s1[16];
#pragma unroll
    for (int r = 0; r < 16; ++r) { s0[r] = 0.f; s1[r] = 0.f; }

    const int i0 = chunk * ICH_;
    for (int ii = 0; ii < ICH_; ++ii) {
        const int i = i0 + ii;
        const _Float16* xb = Xh + (size_t)i * (B_ * L_);
        half8_t xf0 = *(const half8_t*)(xb + kb * L_ + 8 * h2);
        half8_t xf1 = *(const half8_t*)(xb + (32 + kb) * L_ + 8 * h2);
        half8_t af = *(const half8_t*)(Wh + ((size_t)(i * J_ + j) * K_ + kb) * L_ + 8 * h2);
        const _Float16* ep = ebuf + ((size_t)j * I_ + i) * B_;
        const float c0 = (float)ep[kb] * __builtin_amdgcn_rcpf(D[(size_t)i * B_ + kb]);
        const float c1 = (float)ep[32 + kb] * __builtin_amdgcn_rcpf(D[(size_t)i * B_ + 32 + kb]);
        f32x16 acc0 = __builtin_amdgcn_mfma_f32_32x32x16_f16(af, xf0, fzero16(), 0, 0, 0);
        f32x16 acc1 = __builtin_amdgcn_mfma_f32_32x32x16_f16(af, xf1, fzero16(), 0, 0, 0);
#pragma unroll
        for (int r = 0; r < 16; ++r) {
            s0[r] += c0 * acc0[r];
            s1[r] += c1 * acc1[r];
        }
    }
    // coalesced flush: parts[chunk][j][k][b]
#pragma unroll
    for (int r = 0; r < 16; ++r) {
        const int k = (r & 3) + 8 * (r >> 2) + 4 * h2;
        _Float16* p = parts + (((size_t)chunk * J_ + j) * K_ + k) * B_;
        p[kb] = (_Float16)s0[r];
        p[32 + kb] = (_Float16)s1[r];
    }
}

// ---- reduce: block = j (grid 64), 512 threads: b = t&63, kg = t>>6, k = kg*4+q.
// Coalesced parts reads. Squash over k via tiny LDS. Zeros D for the next
// iteration when STEP < 2 (runs before the zcalc that atomically accumulates).
// STEP0: s *= 1/64, wvz = v. STEP1: wvz += v. STEP2: out = v.
__global__ __launch_bounds__(512) void reduce_kernel(const _Float16* __restrict__ parts,
                                                     _Float16* __restrict__ wvz,
                                                     float* __restrict__ out,
                                                     float* __restrict__ D,
                                                     int STEP) {
    __shared__ float ssql[8][64];
    const int j = blockIdx.x;
    const int t = threadIdx.x;
    const int b = t & 63;
    const int kg = t >> 6;  // k = kg*4 + q, q in [0,4)

    if (STEP < 2) {
        // zero D: 131072 floats over 64 blocks x 512 threads = float4 per thread
        float4_t zz = {0.f, 0.f, 0.f, 0.f};
        ((float4_t*)D)[(size_t)j * 512 + t] = zz;
    }

    float acc[4] = {0.f, 0.f, 0.f, 0.f};
    for (int ch = 0; ch < SCH_; ++ch) {
        const _Float16* p = parts + (((size_t)ch * J_ + j) * K_ + kg * 4) * B_ + b;
#pragma unroll
        for (int q = 0; q < 4; ++q) acc[q] += (float)p[(size_t)q * B_];
    }
    if (STEP == 0) {
#pragma unroll
        for (int q = 0; q < 4; ++q) acc[q] *= (1.0f / 64.0f);
    }
    ssql[kg][b] = acc[0] * acc[0] + acc[1] * acc[1] + acc[2] * acc[2] + acc[3] * acc[3];
    __syncthreads();
    float sq = 0.f;
#pragma unroll
    for (int g = 0; g < 8; ++g) sq += ssql[g][b];
    const float scale = sq / (1.0f + sq) / sqrtf(sq + 1e-7f);

    if (STEP == 2) {
#pragma unroll
        for (int q = 0; q < 4; ++q)
            out[(size_t)b * N_ + j * K_ + kg * 4 + q] = acc[q] * scale;
    } else {
        // k = kg*4+q -> h2 = kg&1, r = q + 4*(kg>>1)
        _Float16* wp = wvz + ((size_t)(j * 2 + (kg & 1)) * B_ + b) * 16 + 4 * (kg >> 1);
#pragma unroll
        for (int q = 0; q < 4; ++q) {
            const float prev = (STEP == 0) ? 0.f : (float)wp[q];
            wp[q] = (_Float16)(prev + acc[q] * scale);
        }
    }
}

extern "C" void kernel_launch(void* const* d_in, const int* in_sizes, int n_in,
                              void* d_out, int out_size, void* d_ws, size_t ws_size,
                              hipStream_t stream) {
    const float* X = (const float*)d_in[0];  // [64][2048][16]
    const float* W = (const float*)d_in[1];  // [64][2048][32][16]
    float* out = (float*)d_out;              // [64][64][32]
    char* ws = (char*)d_ws;

    const size_t WH_BYTES = (size_t)I_ * J_ * K_ * L_ * 2;   // 134,217,728
    const size_t XH_BYTES = (size_t)I_ * B_ * L_ * 2;        //   4,194,304
    const size_t WVZ_BYTES = (size_t)J_ * 2 * B_ * 16 * 2;   //     262,144
    const size_t EB_BYTES = (size_t)J_ * I_ * B_ * 2;        //  16,777,216
    const size_t D_BYTES = (size_t)I_ * B_ * 4;              //     524,288
    const size_t FIX = WH_BYTES + XH_BYTES + WVZ_BYTES + EB_BYTES + D_BYTES;

    _Float16* Wh = (_Float16*)ws;
    _Float16* Xh = (_Float16*)(ws + WH_BYTES);
    _Float16* wvz = (_Float16*)(ws + WH_BYTES + XH_BYTES);
    _Float16* ebuf = (_Float16*)(ws + WH_BYTES + XH_BYTES + WVZ_BYTES);
    float* D = (float*)(ws + WH_BYTES + XH_BYTES + WVZ_BYTES + EB_BYTES);
    _Float16* parts = (_Float16*)(ws + FIX);  // SCH_*N_*B_*2 = 8,388,608

    cast_x_kernel<<<dim3((B_ * I_) / 256), dim3(256), 0, stream>>>(X, Xh);

    // r = 0: uniform c; fused fp32 read (nt) + cast + s0
    s0_cast_kernel<<<dim3(SCH_ * 8), dim3(512), 0, stream>>>(W, Wh, Xh, parts);
    reduce_kernel<<<dim3(J_), dim3(512), 0, stream>>>(parts, wvz, out, D, 0);

    // r = 1: e = exp(v0 . u_hat), D accumulated in-kernel; s1
    zcalc_kernel<<<dim3(SCH_ * 8), dim3(512), 0, stream>>>(Wh, Xh, wvz, ebuf, D);
    s_kernel<<<dim3(SCH_ * 8), dim3(512), 0, stream>>>(Wh, Xh, ebuf, D, parts);
    reduce_kernel<<<dim3(J_), dim3(512), 0, stream>>>(parts, wvz, out, D, 1);

    // r = 2: e = exp((v0+v1) . u_hat), D accumulated in-kernel; s2
    zcalc_kernel<<<dim3(SCH_ * 8), dim3(512), 0, stream>>>(Wh, Xh, wvz, ebuf, D);
    s_kernel<<<dim3(SCH_ * 8), dim3(512), 0, stream>>>(Wh, Xh, ebuf, D, parts);
    reduce_kernel<<<dim3(J_), dim3(512), 0, stream>>>(parts, wvz, out, D, 2);

    (void)in_sizes; (void)n_in; (void)out_size; (void)ws_size;
}